// Round 22
// baseline (352.971 us; speedup 1.0000x reference)
//
#include <hip/hip_runtime.h>

// Convolution_1228360646680 — equivariant graph conv
// N=25000, E=400000, MUL=32, NSC=8, HID=64
//
// Fast path (5 dispatches):
//   memset(counts)
//   pre:      fused prep + edge count + node_in (8-row LDS staging)
//   scan:     offs/cursor prefix sum (1 block)
//   scatter:  dst-sorted permutation, payload written directly
//   gather_all: WAVE per node (4/block); per 16-edge chunk the wave
//       (a) computes h=silu(q@W1s) in A-frag layout (validated),
//       (b) 16 MFMAs with register-resident W2 B-frags (validated),
//       (c) C-frags -> wave-PRIVATE 4KB LDS tile (validated bijection, no barrier),
//       (d) consumes via round-20 pipelined loop (wq from LDS, x from L3 xsv1);
//       accs -> smid; fused w2 tail -> out. No wbuf, no edge_mlp kernel.
// Fallback (ws too small): atomic scatter-add + node_out.

typedef __attribute__((ext_vector_type(8))) short bf16x8;
typedef __attribute__((ext_vector_type(4))) float f32x4;

__device__ __forceinline__ unsigned bf16r(float x) {
    unsigned u = __float_as_uint(x);
    return (u + 0x7fffu + ((u >> 16) & 1u)) >> 16;   // RNE
}
__device__ __forceinline__ float bflo(unsigned p) { return __uint_as_float(p << 16); }
__device__ __forceinline__ float bfhi(unsigned p) { return __uint_as_float(p & 0xffff0000u); }

// ---------------- fused: prep + count + node_in (8-row staging) ----------------
__global__ __launch_bounds__(256) void pre_kernel(
    const float* __restrict__ node_input, const float* __restrict__ attr_in,
    const float* __restrict__ w1s, const float* __restrict__ w1v,
    float* __restrict__ xsv1, int n_nodes,
    const float* __restrict__ Wfc1, const float* __restrict__ Wfc2,
    float* __restrict__ W1s, float* __restrict__ W2T, unsigned short* __restrict__ W2Tb,
    const int* __restrict__ edst, int* __restrict__ counts, int n_edges_count)
{
    int t = blockIdx.x * 256 + threadIdx.x;
    const float inv_sqrt_nsc = 0.35355339059327373f; // 1/sqrt(8)
    if (t < 8 * 64) W1s[t] = Wfc1[t] * inv_sqrt_nsc;
    if (t < 64 * 128) {
        int r = t >> 7, c = t & 127;
        float v = Wfc2[t] * 0.125f;                  // 1/sqrt(64)
        W2T[c * 64 + r] = v;
        W2Tb[c * 64 + r] = (unsigned short)bf16r(v);
    }
    for (int e = t; e < n_edges_count; e += gridDim.x * 256)
        atomicAdd(&counts[edst[e]], 1);

    __shared__ float sWs[1024], sWv[1024], srow[8][128];
    for (int k = threadIdx.x; k < 1024; k += 256) { sWs[k] = w1s[k]; sWv[k] = w1v[k]; }
    int tid = threadIdx.x;
    int j = tid & 127;
    int half = tid >> 7;
    int w = 0, i = 0;
    if (j >= 32) { int jj = j - 32; w = jj / 3; i = jj - 3 * w; }
    const float inv1 = 0.17677669529663687f; // 1/sqrt(32)
    for (int base = blockIdx.x * 8; base < n_nodes; base += gridDim.x * 8) {
        __syncthreads();
        for (int idx = tid; idx < 1024; idx += 256) {
            int r = idx >> 7, c = idx & 127;
            int n = base + r;
            if (n < n_nodes) srow[r][c] = node_input[(size_t)n * 128 + c];
        }
        __syncthreads();
        #pragma unroll
        for (int rr = 0; rr < 4; rr++) {
            int r = 2 * rr + half;
            int n = base + r;
            if (n < n_nodes) {
                float acc = 0.0f;
                if (j < 32) {
                    #pragma unroll
                    for (int u = 0; u < 32; u++) acc += srow[r][u] * sWs[u * 32 + j];
                } else {
                    #pragma unroll
                    for (int u = 0; u < 32; u++) acc += srow[r][32 + 3 * u + i] * sWv[u * 32 + w];
                }
                xsv1[(size_t)n * 128 + j] = acc * (attr_in[n] * inv1);
            }
        }
    }
}

// ---------------- CSR build ----------------
__global__ __launch_bounds__(1024) void scan_kernel(
    const int* __restrict__ counts, int* __restrict__ offs, int* __restrict__ cursor, int n)
{
    __shared__ int part[1024];
    int tid = threadIdx.x;
    int chunk = (n + 1023) / 1024;
    int begin = tid * chunk;
    int end = begin + chunk; if (end > n) end = n;
    int s = 0;
    for (int i = begin; i < end; i++) s += counts[i];
    part[tid] = s;
    __syncthreads();
    for (int off = 1; off < 1024; off <<= 1) {
        int v = (tid >= off) ? part[tid - off] : 0;
        __syncthreads();
        part[tid] += v;
        __syncthreads();
    }
    int base = (tid == 0) ? 0 : part[tid - 1];
    for (int i = begin; i < end; i++) {
        offs[i] = base; cursor[i] = base;
        base += counts[i];
    }
    if (tid == 1023) offs[n] = part[1023];
}

__global__ __launch_bounds__(256) void scatter_kernel(
    const int* __restrict__ edst, const int* __restrict__ esrc,
    const float* __restrict__ eattr, const float* __restrict__ escal,
    int* __restrict__ cursor,
    int* __restrict__ esrc_s, float4* __restrict__ eattr_s, float4* __restrict__ escal_s,
    int n_edges)
{
    int e = blockIdx.x * 256 + threadIdx.x;
    if (e < n_edges) {
        int d = edst[e];
        int p = atomicAdd(&cursor[d], 1);
        esrc_s[p] = esrc[e];
        eattr_s[p] = *reinterpret_cast<const float4*>(eattr + (size_t)e * 4);
        escal_s[2 * (size_t)p]     = *reinterpret_cast<const float4*>(escal + (size_t)e * 8);
        escal_s[2 * (size_t)p + 1] = *reinterpret_cast<const float4*>(escal + (size_t)e * 8 + 4);
    }
}

// ---------------- fully fused gather: h + MFMA + tensor product + w2 tail ----------------
__global__ __launch_bounds__(256) void gather_all_kernel(
    const float4* __restrict__ escal_s,
    const float* __restrict__ W1s_g, const unsigned short* __restrict__ W2Tb,
    const float* __restrict__ xsv1, const int* __restrict__ esrc_s,
    const float4* __restrict__ eattr_s, const int* __restrict__ offs,
    const float* __restrict__ attr_out,
    const float* __restrict__ w2s, const float* __restrict__ w2v,
    float* __restrict__ out, int n_nodes)
{
    __shared__ float sW[4096];                     // w2s | w2v
    __shared__ float smid[4][256];
    __shared__ unsigned short wtile[4][2048];      // per-wave C-frag tile (4KB)

    int tid = threadIdx.x;
    for (int idx = tid; idx < 2048; idx += 256) { sW[idx] = w2s[idx]; sW[2048 + idx] = w2v[idx]; }

    int wv = __builtin_amdgcn_readfirstlane(tid >> 6);
    int L = tid & 63;
    int n = blockIdx.x * 4 + wv;
    int lm = L & 15, lk = L >> 4;
    int k0 = lk * 8;

    // B fragments: register-resident W2 (validated layout, 64 VGPR)
    bf16x8 bf[8][2];
    #pragma unroll
    for (int t = 0; t < 8; t++) {
        int nn = t * 16 + lm;
        bf[t][0] = *reinterpret_cast<const bf16x8*>(W2Tb + nn * 64 + k0);
        bf[t][1] = *reinterpret_cast<const bf16x8*>(W2Tb + nn * 64 + k0 + 32);
    }

    // consumer decode (validated mapping)
    int g = L >> 4;
    int be, fbase; bool six;
    if (g == 0)      { be = 2 * L;       fbase = 2 * L;      six = false; }
    else if (g == 1) { be = 2 * L - 32;  fbase = 6 * L - 32; six = true;  }
    else if (g == 2) { be = 6 * L - 160; fbase = 6 * L - 32; six = true;  }
    else             { be = 6 * L - 256; fbase = 2 * L - 64; six = false; }
    const int colpart = ((2 * L) >> 4) * 256 + (((2 * L) & 15) << 2);   // ushort units
    const float inv_sqrt3 = 0.5773502691896258f;
    float a0 = 0.f, a1 = 0.f, a2 = 0.f, a3 = 0.f, a4 = 0.f, a5 = 0.f;

    if (n < n_nodes) {
        int start = offs[n], end = offs[n + 1];
        unsigned short* __restrict__ wt = wtile[wv];

        for (int cbase = start; cbase < end; cbase += 16) {
            int cnt = end - cbase; if (cnt > 16) cnt = 16;

            // ---- producer: h = silu(q @ W1s) for edge cbase+lm (A-frag layout) ----
            float q[8];
            if (lm < cnt) {
                float4 qa = escal_s[2 * (size_t)(cbase + lm)];
                float4 qb = escal_s[2 * (size_t)(cbase + lm) + 1];
                q[0] = qa.x; q[1] = qa.y; q[2] = qa.z; q[3] = qa.w;
                q[4] = qb.x; q[5] = qb.y; q[6] = qb.z; q[7] = qb.w;
            } else {
                #pragma unroll
                for (int z = 0; z < 8; z++) q[z] = 0.f;
            }
            union Af { bf16x8 v; unsigned u[4]; };
            Af af0, af1;
            #pragma unroll
            for (int half = 0; half < 2; half++) {
                int kb = k0 + half * 32;
                float h[8];
                #pragma unroll
                for (int z = 0; z < 8; z++) h[z] = 0.f;
                #pragma unroll
                for (int in = 0; in < 8; in++) {
                    float qi = q[in];
                    float4 wa = *reinterpret_cast<const float4*>(W1s_g + in * 64 + kb);
                    float4 wb = *reinterpret_cast<const float4*>(W1s_g + in * 64 + kb + 4);
                    h[0] += qi * wa.x; h[1] += qi * wa.y; h[2] += qi * wa.z; h[3] += qi * wa.w;
                    h[4] += qi * wb.x; h[5] += qi * wb.y; h[6] += qi * wb.z; h[7] += qi * wb.w;
                }
                unsigned* dst = half ? af1.u : af0.u;
                #pragma unroll
                for (int p = 0; p < 4; p++) {
                    float s0 = h[2 * p], s1 = h[2 * p + 1];
                    s0 = s0 / (1.0f + __expf(-s0));
                    s1 = s1 / (1.0f + __expf(-s1));
                    dst[p] = bf16r(s0) | (bf16r(s1) << 16);
                }
            }

            // ---- MFMA -> wave-private LDS tile (validated bijection) ----
            #pragma unroll
            for (int t = 0; t < 8; t++) {
                f32x4 a4 = {0.f, 0.f, 0.f, 0.f};
                a4 = __builtin_amdgcn_mfma_f32_16x16x32_bf16(af0.v, bf[t][0], a4, 0, 0, 0);
                a4 = __builtin_amdgcn_mfma_f32_16x16x32_bf16(af1.v, bf[t][1], a4, 0, 0, 0);
                unsigned s0 = bf16r(a4[0]) | (bf16r(a4[1]) << 16);
                unsigned s1 = bf16r(a4[2]) | (bf16r(a4[3]) << 16);
                *reinterpret_cast<uint2*>(&wt[t * 256 + L * 4]) = make_uint2(s0, s1);
            }

            // ---- consumer: round-20 pipelined loop, wq from LDS (local index m) ----
            #define GCOMP(EA, WQ, SEL, X0, X1, X2)                                            \
            {                                                                                 \
                unsigned ulo = ((SEL) & 2) ? (WQ).y : (WQ).x;                                 \
                unsigned uhi = ((SEL) & 2) ? (WQ).w : (WQ).z;                                 \
                float wlo = ((SEL) & 1) ? bfhi(ulo) : bflo(ulo);                              \
                float whi = ((SEL) & 1) ? bfhi(uhi) : bflo(uhi);                              \
                if (g == 0) {                                                                 \
                    a0 += wlo * (X0).x * (EA).x;                                              \
                    a1 += whi * (X0).y * (EA).x;                                              \
                } else if (g == 1) {                                                          \
                    float b0 = wlo * (X0).x, b1 = whi * (X0).y;                               \
                    a0 += b0 * (EA).y; a1 += b0 * (EA).z; a2 += b0 * (EA).w;                  \
                    a3 += b1 * (EA).y; a4 += b1 * (EA).z; a5 += b1 * (EA).w;                  \
                } else if (g == 2) {                                                          \
                    float b0 = wlo * (EA).x, b1 = whi * (EA).x;                               \
                    a0 += b0 * (X0).x; a1 += b0 * (X0).y; a2 += b0 * (X1).x;                  \
                    a3 += b1 * (X1).y; a4 += b1 * (X2).x; a5 += b1 * (X2).y;                  \
                } else {                                                                      \
                    a0 += wlo * ((X0).x * (EA).y + (X0).y * (EA).z + (X1).x * (EA).w) * inv_sqrt3; \
                    a1 += whi * ((X1).y * (EA).y + (X2).x * (EA).z + (X2).y * (EA).w) * inv_sqrt3; \
                }                                                                             \
            }

            {
                float4 eaA; uint4 wqA; int selA; float2 xA0, xA1, xA2;
                {
                    int srcA = esrc_s[cbase];
                    eaA = eattr_s[cbase];
                    selA = 0;
                    wqA = *reinterpret_cast<const uint4*>(&wt[colpart]);
                    const float* __restrict__ nbA = xsv1 + (size_t)srcA * 128;
                    xA0 = *reinterpret_cast<const float2*>(nbA + be);
                    xA1 = *reinterpret_cast<const float2*>(nbA + be + 2);
                    xA2 = *reinterpret_cast<const float2*>(nbA + be + 4);
                }
                int srcB = esrc_s[cbase + 1];       // esrc_s padded +4: safe
                for (int m = 1; m < cnt; m++) {
                    int k = cbase + m;
                    float4 eaB = eattr_s[k];
                    int selB = m & 3;
                    uint4 wqB = *reinterpret_cast<const uint4*>(&wt[colpart + ((m >> 2) << 6)]);
                    const float* __restrict__ nbB = xsv1 + (size_t)srcB * 128;
                    float2 xB0 = *reinterpret_cast<const float2*>(nbB + be);
                    float2 xB1 = *reinterpret_cast<const float2*>(nbB + be + 2);
                    float2 xB2 = *reinterpret_cast<const float2*>(nbB + be + 4);
                    int srcC = esrc_s[k + 1];       // padded: safe
                    GCOMP(eaA, wqA, selA, xA0, xA1, xA2);
                    eaA = eaB; wqA = wqB; selA = selB;
                    xA0 = xB0; xA1 = xB1; xA2 = xB2;
                    srcB = srcC;
                }
                GCOMP(eaA, wqA, selA, xA0, xA1, xA2);
            }
            #undef GCOMP
        }
    }

    float* row = &smid[wv][fbase];
    row[0] = a0; row[1] = a1;
    if (six) { row[2] = a2; row[3] = a3; row[4] = a4; row[5] = a5; }
    __syncthreads();   // covers sW staging + smid writes

    int h = tid >> 7, j = tid & 127;
    int tw = 0, ti = 0;
    if (j >= 32) { int jj = j - 32; tw = jj / 3; ti = jj - 3 * tw; }
    #pragma unroll
    for (int it = 0; it < 2; it++) {
        int ln = 2 * it + h;
        int nn = blockIdx.x * 4 + ln;
        if (nn < n_nodes) {
            const float* __restrict__ sm = smid[ln];
            float o = 0.0f;
            if (j < 32) {
                #pragma unroll
                for (int u = 0; u < 32; u++)
                    o += sm[u] * sW[u * 32 + j] + sm[32 + u] * sW[1024 + u * 32 + j];
            } else {
                #pragma unroll
                for (int u = 0; u < 32; u++)
                    o += sm[64 + 3 * u + ti] * sW[2048 + u * 32 + tw]
                       + sm[160 + 3 * u + ti] * sW[3072 + u * 32 + tw];
            }
            out[(size_t)nn * 128 + j] = o * (attr_out[nn] * 0.03125f); // 1/sqrt(64)/sqrt(16)
        }
    }
}

// ---------------- fallback atomic edge kernel (ws too small) ----------------
__global__ __launch_bounds__(256) void edge_kernel_atomic(
    const float* __restrict__ xsv1, const int* __restrict__ esrc, const int* __restrict__ edst,
    const float* __restrict__ eattr, const float* __restrict__ escal,
    const float* __restrict__ W1s, const float* __restrict__ W2T,
    float* __restrict__ mid, int n_edges)
{
    int e = blockIdx.x * 256 + threadIdx.x;
    if (e >= n_edges) return;
    const float4 qa = *reinterpret_cast<const float4*>(escal + (size_t)e * 8);
    const float4 qb = *reinterpret_cast<const float4*>(escal + (size_t)e * 8 + 4);
    float h[64];
    #pragma unroll
    for (int t = 0; t < 64; t++) {
        float acc = qa.x * W1s[t]       + qa.y * W1s[64 + t]
                  + qa.z * W1s[128 + t] + qa.w * W1s[192 + t]
                  + qb.x * W1s[256 + t] + qb.y * W1s[320 + t]
                  + qb.z * W1s[384 + t] + qb.w * W1s[448 + t];
        h[t] = acc / (1.0f + __expf(-acc));
    }
    int src = esrc[e], dst = edst[e];
    const float4 ea = *reinterpret_cast<const float4*>(eattr + (size_t)e * 4);
    const float ys = ea.x, yv0 = ea.y, yv1 = ea.z, yv2 = ea.w;
    const float* __restrict__ nb = xsv1 + (size_t)src * 128;
    float* __restrict__ op = mid + (size_t)dst * 256;
    const float inv_sqrt3 = 0.5773502691896258f;
    for (int u = 0; u < 32; u++) {
        float w0 = 0.f, w1 = 0.f, w2 = 0.f, w3 = 0.f;
        const float* __restrict__ r0 = W2T + (size_t)u * 64;
        const float* __restrict__ r1 = W2T + (size_t)(32 + u) * 64;
        const float* __restrict__ r2 = W2T + (size_t)(64 + u) * 64;
        const float* __restrict__ r3 = W2T + (size_t)(96 + u) * 64;
        #pragma unroll
        for (int t = 0; t < 64; t++) {
            float hv = h[t];
            w0 += hv * r0[t]; w1 += hv * r1[t]; w2 += hv * r2[t]; w3 += hv * r3[t];
        }
        float es  = nb[u];
        float ev0 = nb[32 + 3 * u], ev1 = nb[33 + 3 * u], ev2 = nb[34 + 3 * u];
        atomicAdd(op + u,      w0 * es * ys);
        atomicAdd(op + 32 + u, w3 * (ev0 * yv0 + ev1 * yv1 + ev2 * yv2) * inv_sqrt3);
        float a1 = w1 * es;
        atomicAdd(op + 64 + 3 * u, a1 * yv0);
        atomicAdd(op + 65 + 3 * u, a1 * yv1);
        atomicAdd(op + 66 + 3 * u, a1 * yv2);
        float a2 = w2 * ys;
        atomicAdd(op + 160 + 3 * u, a2 * ev0);
        atomicAdd(op + 161 + 3 * u, a2 * ev1);
        atomicAdd(op + 162 + 3 * u, a2 * ev2);
    }
}

__global__ __launch_bounds__(256) void node_out_kernel(
    const float* __restrict__ mid, const float* __restrict__ attr_out,
    const float* __restrict__ w2s, const float* __restrict__ w2v,
    float* __restrict__ out, int n_nodes)
{
    __shared__ float sS0[1024], sS1[1024], sV0[1024], sV1[1024];
    for (int k = threadIdx.x; k < 1024; k += 256) {
        sS0[k] = w2s[k]; sS1[k] = w2s[1024 + k];
        sV0[k] = w2v[k]; sV1[k] = w2v[1024 + k];
    }
    __syncthreads();
    int j = threadIdx.x & 127;
    int half = threadIdx.x >> 7;
    int w = 0, i = 0;
    if (j >= 32) { int jj = j - 32; w = jj / 3; i = jj - 3 * w; }
    const float scale = 0.125f * 0.25f;
    for (int base = blockIdx.x * 2; base < n_nodes; base += gridDim.x * 2) {
        int n = base + half;
        if (n >= n_nodes) continue;
        const float* __restrict__ mr = mid + (size_t)n * 256;
        float acc = 0.0f;
        if (j < 32) {
            #pragma unroll
            for (int u = 0; u < 32; u++)
                acc += mr[u] * sS0[u * 32 + j] + mr[32 + u] * sS1[u * 32 + j];
        } else {
            #pragma unroll
            for (int u = 0; u < 32; u++)
                acc += mr[64 + 3 * u + i] * sV0[u * 32 + w] + mr[160 + 3 * u + i] * sV1[u * 32 + w];
        }
        out[(size_t)n * 128 + j] = acc * (attr_out[n] * scale);
    }
}

extern "C" void kernel_launch(void* const* d_in, const int* in_sizes, int n_in,
                              void* d_out, int out_size, void* d_ws, size_t ws_size,
                              hipStream_t stream)
{
    const float* node_input = (const float*)d_in[0];
    const float* attr_in    = (const float*)d_in[1];
    const float* attr_out   = (const float*)d_in[2];
    const int*   esrc       = (const int*)d_in[3];
    const int*   edst       = (const int*)d_in[4];
    const float* eattr      = (const float*)d_in[5];
    const float* escal      = (const float*)d_in[6];
    const float* w1s        = (const float*)d_in[7];
    const float* w1v        = (const float*)d_in[8];
    const float* Wfc1       = (const float*)d_in[9];
    const float* Wfc2       = (const float*)d_in[10];
    const float* w2s        = (const float*)d_in[11];
    const float* w2v        = (const float*)d_in[12];
    float* out = (float*)d_out;

    int n_nodes = in_sizes[0] / 128;
    int n_edges = in_sizes[3];

    char* p = (char*)d_ws;
    auto alloc = [&](size_t bytes, size_t align) -> void* {
        size_t a = (size_t)p; a = (a + align - 1) & ~(align - 1);
        p = (char*)a; void* r = (void*)p; p += bytes; return r;
    };
    float* xsv1 = (float*)alloc((size_t)n_nodes * 128 * 4, 16);
    float* W1s  = (float*)alloc(512 * 4, 16);
    float* W2T  = (float*)alloc(8192 * 4, 16);
    float* mid  = (float*)alloc((size_t)n_nodes * 256 * 4, 16);   // fallback only
    int* counts = (int*)alloc((size_t)n_nodes * 4, 16);
    int* offs   = (int*)alloc(((size_t)n_nodes + 1) * 4, 16);
    int* cursor = (int*)alloc((size_t)n_nodes * 4, 16);
    int* esrc_s = (int*)alloc(((size_t)n_edges + 4) * 4, 16);     // +4 lookahead pad
    float4* eattr_s = (float4*)alloc((size_t)n_edges * 16, 16);
    float4* escal_s = (float4*)alloc((size_t)n_edges * 32, 16);
    unsigned short* W2Tb = (unsigned short*)alloc(8192 * 2, 64);
    size_t needed = (size_t)(p - (char*)d_ws);

    if (ws_size >= needed) {
        hipMemsetAsync(counts, 0, (size_t)n_nodes * sizeof(int), stream);
        pre_kernel<<<2048, 256, 0, stream>>>(
            node_input, attr_in, w1s, w1v, xsv1, n_nodes,
            Wfc1, Wfc2, W1s, W2T, W2Tb, edst, counts, n_edges);
        scan_kernel<<<1, 1024, 0, stream>>>(counts, offs, cursor, n_nodes);
        scatter_kernel<<<(n_edges + 255) / 256, 256, 0, stream>>>(
            edst, esrc, eattr, escal, cursor, esrc_s, eattr_s, escal_s, n_edges);
        gather_all_kernel<<<(n_nodes + 3) / 4, 256, 0, stream>>>(
            escal_s, W1s, W2Tb, xsv1, esrc_s, eattr_s, offs,
            attr_out, w2s, w2v, out, n_nodes);
    } else {
        pre_kernel<<<2048, 256, 0, stream>>>(
            node_input, attr_in, w1s, w1v, xsv1, n_nodes,
            Wfc1, Wfc2, W1s, W2T, W2Tb, edst, counts, 0 /*no count*/);
        hipMemsetAsync(mid, 0, (size_t)n_nodes * 256 * sizeof(float), stream);
        edge_kernel_atomic<<<(n_edges + 255) / 256, 256, 0, stream>>>(
            xsv1, esrc, edst, eattr, escal, W1s, W2T, mid, n_edges);
        node_out_kernel<<<2048, 256, 0, stream>>>(mid, attr_out, w2s, w2v, out, n_nodes);
    }
}

// Round 23
// 246.751 us; speedup vs baseline: 1.4305x; 1.4305x over previous
//
#include <hip/hip_runtime.h>

// Convolution_1228360646680 — equivariant graph conv
// N=25000, E=400000, MUL=32, NSC=8, HID=64
//
// Fast path (6 dispatches) — best validated configuration (rounds 20/21, 248 µs):
//   memset(counts)
//   pre:      fused prep + edge count + node_in (8-row LDS staging)
//   scan:     offs/cursor prefix sum (1 block)
//   scatter:  dst-sorted permutation, payload written directly
//   edge_mlp_v4: wave = 8 consecutive 16-edge tiles; B-frags once/wave;
//             C-frags RAW tile layout (coalesced uint2, no LDS)
//   gather_out: WAVE per node (4/block); named-register 1-edge-ahead prefetch;
//             branch-free x loads; accs -> LDS smid; fused w2 tail -> out.
// Fallback (ws too small): atomic scatter-add + node_out.

typedef __attribute__((ext_vector_type(8))) short bf16x8;
typedef __attribute__((ext_vector_type(4))) float f32x4;

__device__ __forceinline__ unsigned bf16r(float x) {
    unsigned u = __float_as_uint(x);
    return (u + 0x7fffu + ((u >> 16) & 1u)) >> 16;   // RNE
}
__device__ __forceinline__ float bflo(unsigned p) { return __uint_as_float(p << 16); }
__device__ __forceinline__ float bfhi(unsigned p) { return __uint_as_float(p & 0xffff0000u); }

// ---------------- fused: prep + count + node_in (8-row staging) ----------------
__global__ __launch_bounds__(256) void pre_kernel(
    const float* __restrict__ node_input, const float* __restrict__ attr_in,
    const float* __restrict__ w1s, const float* __restrict__ w1v,
    float* __restrict__ xsv1, int n_nodes,
    const float* __restrict__ Wfc1, const float* __restrict__ Wfc2,
    float* __restrict__ W1s, float* __restrict__ W2T, unsigned short* __restrict__ W2Tb,
    const int* __restrict__ edst, int* __restrict__ counts, int n_edges_count)
{
    int t = blockIdx.x * 256 + threadIdx.x;
    const float inv_sqrt_nsc = 0.35355339059327373f; // 1/sqrt(8)
    if (t < 8 * 64) W1s[t] = Wfc1[t] * inv_sqrt_nsc;
    if (t < 64 * 128) {
        int r = t >> 7, c = t & 127;
        float v = Wfc2[t] * 0.125f;                  // 1/sqrt(64)
        W2T[c * 64 + r] = v;
        W2Tb[c * 64 + r] = (unsigned short)bf16r(v);
    }
    for (int e = t; e < n_edges_count; e += gridDim.x * 256)
        atomicAdd(&counts[edst[e]], 1);

    __shared__ float sWs[1024], sWv[1024], srow[8][128];
    for (int k = threadIdx.x; k < 1024; k += 256) { sWs[k] = w1s[k]; sWv[k] = w1v[k]; }
    int tid = threadIdx.x;
    int j = tid & 127;
    int half = tid >> 7;
    int w = 0, i = 0;
    if (j >= 32) { int jj = j - 32; w = jj / 3; i = jj - 3 * w; }
    const float inv1 = 0.17677669529663687f; // 1/sqrt(32)
    for (int base = blockIdx.x * 8; base < n_nodes; base += gridDim.x * 8) {
        __syncthreads();   // guards srow reuse (and sWs/sWv on first iter)
        for (int idx = tid; idx < 1024; idx += 256) {
            int r = idx >> 7, c = idx & 127;
            int n = base + r;
            if (n < n_nodes) srow[r][c] = node_input[(size_t)n * 128 + c];
        }
        __syncthreads();
        #pragma unroll
        for (int rr = 0; rr < 4; rr++) {
            int r = 2 * rr + half;
            int n = base + r;
            if (n < n_nodes) {
                float acc = 0.0f;
                if (j < 32) {
                    #pragma unroll
                    for (int u = 0; u < 32; u++) acc += srow[r][u] * sWs[u * 32 + j];
                } else {
                    #pragma unroll
                    for (int u = 0; u < 32; u++) acc += srow[r][32 + 3 * u + i] * sWv[u * 32 + w];
                }
                xsv1[(size_t)n * 128 + j] = acc * (attr_in[n] * inv1);
            }
        }
    }
}

// ---------------- CSR build ----------------
__global__ __launch_bounds__(1024) void scan_kernel(
    const int* __restrict__ counts, int* __restrict__ offs, int* __restrict__ cursor, int n)
{
    __shared__ int part[1024];
    int tid = threadIdx.x;
    int chunk = (n + 1023) / 1024;
    int begin = tid * chunk;
    int end = begin + chunk; if (end > n) end = n;
    int s = 0;
    for (int i = begin; i < end; i++) s += counts[i];
    part[tid] = s;
    __syncthreads();
    for (int off = 1; off < 1024; off <<= 1) {
        int v = (tid >= off) ? part[tid - off] : 0;
        __syncthreads();
        part[tid] += v;
        __syncthreads();
    }
    int base = (tid == 0) ? 0 : part[tid - 1];
    for (int i = begin; i < end; i++) {
        offs[i] = base; cursor[i] = base;
        base += counts[i];
    }
    if (tid == 1023) offs[n] = part[1023];
}

__global__ __launch_bounds__(256) void scatter_kernel(
    const int* __restrict__ edst, const int* __restrict__ esrc,
    const float* __restrict__ eattr, const float* __restrict__ escal,
    int* __restrict__ cursor,
    int* __restrict__ esrc_s, float4* __restrict__ eattr_s, float4* __restrict__ escal_s,
    int n_edges)
{
    int e = blockIdx.x * 256 + threadIdx.x;
    if (e < n_edges) {
        int d = edst[e];
        int p = atomicAdd(&cursor[d], 1);
        esrc_s[p] = esrc[e];
        eattr_s[p] = *reinterpret_cast<const float4*>(eattr + (size_t)e * 4);
        escal_s[2 * (size_t)p]     = *reinterpret_cast<const float4*>(escal + (size_t)e * 8);
        escal_s[2 * (size_t)p + 1] = *reinterpret_cast<const float4*>(escal + (size_t)e * 8 + 4);
    }
}

// ---------------- edge MLP via MFMA, 8 tiles/wave -> raw C-frag tile layout ----------------
// wbuf[(rt*8+ct)*256 + l*4 + reg], l = ((m>>2)<<4)|nn, reg = m&3  (m=k&15, nn=col&15)
#define TPW 8
__global__ __launch_bounds__(256) void edge_mlp_v4(
    const float4* __restrict__ escal_s,
    const float* __restrict__ W1s, const unsigned short* __restrict__ W2Tb,
    unsigned short* __restrict__ wbuf, int n_edges, int nrt)
{
    int tid = threadIdx.x;
    int wv = tid >> 6, l = tid & 63;
    int lm = l & 15, lk = l >> 4;
    int k0 = lk * 8;
    int rt0 = (blockIdx.x * 4 + wv) * TPW;

    bf16x8 bf[8][2];
    #pragma unroll
    for (int t = 0; t < 8; t++) {
        int n = t * 16 + lm;
        bf[t][0] = *reinterpret_cast<const bf16x8*>(W2Tb + n * 64 + k0);
        bf[t][1] = *reinterpret_cast<const bf16x8*>(W2Tb + n * 64 + k0 + 32);
    }

    #pragma unroll 2
    for (int t8 = 0; t8 < TPW; t8++) {
        int rt = rt0 + t8;
        if (rt >= nrt) break;
        int kidx = rt * 16 + lm;

        float q[8];
        if (kidx < n_edges) {
            float4 qa = escal_s[2 * (size_t)kidx];
            float4 qb = escal_s[2 * (size_t)kidx + 1];
            q[0] = qa.x; q[1] = qa.y; q[2] = qa.z; q[3] = qa.w;
            q[4] = qb.x; q[5] = qb.y; q[6] = qb.z; q[7] = qb.w;
        } else {
            #pragma unroll
            for (int i = 0; i < 8; i++) q[i] = 0.f;
        }

        union Af { bf16x8 v; unsigned u[4]; };
        Af af0, af1;
        #pragma unroll
        for (int half = 0; half < 2; half++) {
            int kb = k0 + half * 32;
            float h[8];
            #pragma unroll
            for (int i = 0; i < 8; i++) h[i] = 0.f;
            #pragma unroll
            for (int in = 0; in < 8; in++) {
                float qi = q[in];
                float4 wa = *reinterpret_cast<const float4*>(W1s + in * 64 + kb);
                float4 wb = *reinterpret_cast<const float4*>(W1s + in * 64 + kb + 4);
                h[0] += qi * wa.x; h[1] += qi * wa.y; h[2] += qi * wa.z; h[3] += qi * wa.w;
                h[4] += qi * wb.x; h[5] += qi * wb.y; h[6] += qi * wb.z; h[7] += qi * wb.w;
            }
            unsigned* dst = half ? af1.u : af0.u;
            #pragma unroll
            for (int p = 0; p < 4; p++) {
                float s0 = h[2 * p], s1 = h[2 * p + 1];
                s0 = s0 / (1.0f + __expf(-s0));
                s1 = s1 / (1.0f + __expf(-s1));
                dst[p] = bf16r(s0) | (bf16r(s1) << 16);
            }
        }

        #pragma unroll
        for (int t = 0; t < 8; t++) {
            f32x4 a4 = {0.f, 0.f, 0.f, 0.f};
            a4 = __builtin_amdgcn_mfma_f32_16x16x32_bf16(af0.v, bf[t][0], a4, 0, 0, 0);
            a4 = __builtin_amdgcn_mfma_f32_16x16x32_bf16(af1.v, bf[t][1], a4, 0, 0, 0);
            unsigned s0 = bf16r(a4[0]) | (bf16r(a4[1]) << 16);
            unsigned s1 = bf16r(a4[2]) | (bf16r(a4[3]) << 16);
            *reinterpret_cast<uint2*>(wbuf + ((size_t)(rt * 8 + t) * 256) + l * 4) = make_uint2(s0, s1);
        }
    }
}

// ---------------- gather + fused node_out: wave/node, 4/block, named-reg prefetch ----------------
__global__ __launch_bounds__(256) void gather_out_kernel(
    const unsigned short* __restrict__ wbuf, const float* __restrict__ xsv1,
    const int* __restrict__ esrc_s, const float4* __restrict__ eattr_s,
    const int* __restrict__ offs, const float* __restrict__ attr_out,
    const float* __restrict__ w2s, const float* __restrict__ w2v,
    float* __restrict__ out, int n_nodes)
{
    __shared__ float sW[4096];        // w2s (2048) | w2v (2048)
    __shared__ float smid[4][256];

    int tid = threadIdx.x;
    for (int idx = tid; idx < 2048; idx += 256) { sW[idx] = w2s[idx]; sW[2048 + idx] = w2v[idx]; }

    int wv = __builtin_amdgcn_readfirstlane(tid >> 6);
    int L = tid & 63;
    int n = blockIdx.x * 4 + wv;
    int g = L >> 4;

    int be, fbase; bool six;
    if (g == 0)      { be = 2 * L;       fbase = 2 * L;      six = false; }
    else if (g == 1) { be = 2 * L - 32;  fbase = 6 * L - 32; six = true;  }
    else if (g == 2) { be = 6 * L - 160; fbase = 6 * L - 32; six = true;  }
    else             { be = 6 * L - 256; fbase = 2 * L - 64; six = false; }

    const int colpart = ((2 * L) >> 4) * 256 + (((2 * L) & 15) << 2);
    const float inv_sqrt3 = 0.5773502691896258f;
    float a0 = 0.f, a1 = 0.f, a2 = 0.f, a3 = 0.f, a4 = 0.f, a5 = 0.f;

    if (n < n_nodes) {
        int start = offs[n], end = offs[n + 1];

        // load edge kk's operands into named regs (branch-free; be+5 < 128 for all g)
        #define GLOAD(EA, WQ, SEL, X0, X1, X2, KK)                                        \
        {                                                                                 \
            EA = eattr_s[KK];                                                             \
            int epart_ = ((KK) >> 4) * 2048 + ((((KK) >> 2) & 3) << 6);                   \
            SEL = (KK) & 3;                                                               \
            WQ = *reinterpret_cast<const uint4*>(wbuf + (size_t)epart_ + colpart);        \
            int src_ = esrc_s[KK];                                                        \
            const float* __restrict__ nb_ = xsv1 + (size_t)src_ * 128;                    \
            X0 = *reinterpret_cast<const float2*>(nb_ + be);                              \
            X1 = *reinterpret_cast<const float2*>(nb_ + be + 2);                          \
            X2 = *reinterpret_cast<const float2*>(nb_ + be + 4);                          \
        }

        #define GCOMP(EA, WQ, SEL, X0, X1, X2)                                            \
        {                                                                                 \
            unsigned ulo = ((SEL) & 2) ? (WQ).y : (WQ).x;                                 \
            unsigned uhi = ((SEL) & 2) ? (WQ).w : (WQ).z;                                 \
            float wlo = ((SEL) & 1) ? bfhi(ulo) : bflo(ulo);                              \
            float whi = ((SEL) & 1) ? bfhi(uhi) : bflo(uhi);                              \
            if (g == 0) {                                                                 \
                a0 += wlo * (X0).x * (EA).x;                                              \
                a1 += whi * (X0).y * (EA).x;                                              \
            } else if (g == 1) {                                                          \
                float b0 = wlo * (X0).x, b1 = whi * (X0).y;                               \
                a0 += b0 * (EA).y; a1 += b0 * (EA).z; a2 += b0 * (EA).w;                  \
                a3 += b1 * (EA).y; a4 += b1 * (EA).z; a5 += b1 * (EA).w;                  \
            } else if (g == 2) {                                                          \
                float b0 = wlo * (EA).x, b1 = whi * (EA).x;                               \
                a0 += b0 * (X0).x; a1 += b0 * (X0).y; a2 += b0 * (X1).x;                  \
                a3 += b1 * (X1).y; a4 += b1 * (X2).x; a5 += b1 * (X2).y;                  \
            } else {                                                                      \
                a0 += wlo * ((X0).x * (EA).y + (X0).y * (EA).z + (X1).x * (EA).w) * inv_sqrt3; \
                a1 += whi * ((X1).y * (EA).y + (X2).x * (EA).z + (X2).y * (EA).w) * inv_sqrt3; \
            }                                                                             \
        }

        if (start < end) {
            float4 eaA; uint4 wqA; int selA; float2 xA0, xA1, xA2;
            float4 eaB; uint4 wqB; int selB; float2 xB0, xB1, xB2;
            GLOAD(eaA, wqA, selA, xA0, xA1, xA2, start);
            for (int k = start + 1; k < end; k++) {
                GLOAD(eaB, wqB, selB, xB0, xB1, xB2, k);     // prefetch next
                GCOMP(eaA, wqA, selA, xA0, xA1, xA2);        // compute current
                eaA = eaB; wqA = wqB; selA = selB;           // rotate (reg moves)
                xA0 = xB0; xA1 = xB1; xA2 = xB2;
            }
            GCOMP(eaA, wqA, selA, xA0, xA1, xA2);
        }
        #undef GLOAD
        #undef GCOMP
    }

    float* row = &smid[wv][fbase];
    row[0] = a0; row[1] = a1;
    if (six) { row[2] = a2; row[3] = a3; row[4] = a4; row[5] = a5; }
    __syncthreads();   // covers sW staging + smid writes

    int h = tid >> 7, j = tid & 127;
    int tw = 0, ti = 0;
    if (j >= 32) { int jj = j - 32; tw = jj / 3; ti = jj - 3 * tw; }
    #pragma unroll
    for (int it = 0; it < 2; it++) {
        int ln = 2 * it + h;
        int nn = blockIdx.x * 4 + ln;
        if (nn < n_nodes) {
            const float* __restrict__ sm = smid[ln];
            float o = 0.0f;
            if (j < 32) {
                #pragma unroll
                for (int u = 0; u < 32; u++)
                    o += sm[u] * sW[u * 32 + j] + sm[32 + u] * sW[1024 + u * 32 + j];
            } else {
                #pragma unroll
                for (int u = 0; u < 32; u++)
                    o += sm[64 + 3 * u + ti] * sW[2048 + u * 32 + tw]
                       + sm[160 + 3 * u + ti] * sW[3072 + u * 32 + tw];
            }
            out[(size_t)nn * 128 + j] = o * (attr_out[nn] * 0.03125f); // 1/sqrt(64)/sqrt(16)
        }
    }
}

// ---------------- fallback atomic edge kernel (ws too small) ----------------
__global__ __launch_bounds__(256) void edge_kernel_atomic(
    const float* __restrict__ xsv1, const int* __restrict__ esrc, const int* __restrict__ edst,
    const float* __restrict__ eattr, const float* __restrict__ escal,
    const float* __restrict__ W1s, const float* __restrict__ W2T,
    float* __restrict__ mid, int n_edges)
{
    int e = blockIdx.x * 256 + threadIdx.x;
    if (e >= n_edges) return;
    const float4 qa = *reinterpret_cast<const float4*>(escal + (size_t)e * 8);
    const float4 qb = *reinterpret_cast<const float4*>(escal + (size_t)e * 8 + 4);
    float h[64];
    #pragma unroll
    for (int t = 0; t < 64; t++) {
        float acc = qa.x * W1s[t]       + qa.y * W1s[64 + t]
                  + qa.z * W1s[128 + t] + qa.w * W1s[192 + t]
                  + qb.x * W1s[256 + t] + qb.y * W1s[320 + t]
                  + qb.z * W1s[384 + t] + qb.w * W1s[448 + t];
        h[t] = acc / (1.0f + __expf(-acc));
    }
    int src = esrc[e], dst = edst[e];
    const float4 ea = *reinterpret_cast<const float4*>(eattr + (size_t)e * 4);
    const float ys = ea.x, yv0 = ea.y, yv1 = ea.z, yv2 = ea.w;
    const float* __restrict__ nb = xsv1 + (size_t)src * 128;
    float* __restrict__ op = mid + (size_t)dst * 256;
    const float inv_sqrt3 = 0.5773502691896258f;
    for (int u = 0; u < 32; u++) {
        float w0 = 0.f, w1 = 0.f, w2 = 0.f, w3 = 0.f;
        const float* __restrict__ r0 = W2T + (size_t)u * 64;
        const float* __restrict__ r1 = W2T + (size_t)(32 + u) * 64;
        const float* __restrict__ r2 = W2T + (size_t)(64 + u) * 64;
        const float* __restrict__ r3 = W2T + (size_t)(96 + u) * 64;
        #pragma unroll
        for (int t = 0; t < 64; t++) {
            float hv = h[t];
            w0 += hv * r0[t]; w1 += hv * r1[t]; w2 += hv * r2[t]; w3 += hv * r3[t];
        }
        float es  = nb[u];
        float ev0 = nb[32 + 3 * u], ev1 = nb[33 + 3 * u], ev2 = nb[34 + 3 * u];
        atomicAdd(op + u,      w0 * es * ys);
        atomicAdd(op + 32 + u, w3 * (ev0 * yv0 + ev1 * yv1 + ev2 * yv2) * inv_sqrt3);
        float a1 = w1 * es;
        atomicAdd(op + 64 + 3 * u, a1 * yv0);
        atomicAdd(op + 65 + 3 * u, a1 * yv1);
        atomicAdd(op + 66 + 3 * u, a1 * yv2);
        float a2 = w2 * ys;
        atomicAdd(op + 160 + 3 * u, a2 * ev0);
        atomicAdd(op + 161 + 3 * u, a2 * ev1);
        atomicAdd(op + 162 + 3 * u, a2 * ev2);
    }
}

__global__ __launch_bounds__(256) void node_out_kernel(
    const float* __restrict__ mid, const float* __restrict__ attr_out,
    const float* __restrict__ w2s, const float* __restrict__ w2v,
    float* __restrict__ out, int n_nodes)
{
    __shared__ float sS0[1024], sS1[1024], sV0[1024], sV1[1024];
    for (int k = threadIdx.x; k < 1024; k += 256) {
        sS0[k] = w2s[k]; sS1[k] = w2s[1024 + k];
        sV0[k] = w2v[k]; sV1[k] = w2v[1024 + k];
    }
    __syncthreads();
    int j = threadIdx.x & 127;
    int half = threadIdx.x >> 7;
    int w = 0, i = 0;
    if (j >= 32) { int jj = j - 32; w = jj / 3; i = jj - 3 * w; }
    const float scale = 0.125f * 0.25f;
    for (int base = blockIdx.x * 2; base < n_nodes; base += gridDim.x * 2) {
        int n = base + half;
        if (n >= n_nodes) continue;
        const float* __restrict__ mr = mid + (size_t)n * 256;
        float acc = 0.0f;
        if (j < 32) {
            #pragma unroll
            for (int u = 0; u < 32; u++)
                acc += mr[u] * sS0[u * 32 + j] + mr[32 + u] * sS1[u * 32 + j];
        } else {
            #pragma unroll
            for (int u = 0; u < 32; u++)
                acc += mr[64 + 3 * u + i] * sV0[u * 32 + w] + mr[160 + 3 * u + i] * sV1[u * 32 + w];
        }
        out[(size_t)n * 128 + j] = acc * (attr_out[n] * scale);
    }
}

extern "C" void kernel_launch(void* const* d_in, const int* in_sizes, int n_in,
                              void* d_out, int out_size, void* d_ws, size_t ws_size,
                              hipStream_t stream)
{
    const float* node_input = (const float*)d_in[0];
    const float* attr_in    = (const float*)d_in[1];
    const float* attr_out   = (const float*)d_in[2];
    const int*   esrc       = (const int*)d_in[3];
    const int*   edst       = (const int*)d_in[4];
    const float* eattr      = (const float*)d_in[5];
    const float* escal      = (const float*)d_in[6];
    const float* w1s        = (const float*)d_in[7];
    const float* w1v        = (const float*)d_in[8];
    const float* Wfc1       = (const float*)d_in[9];
    const float* Wfc2       = (const float*)d_in[10];
    const float* w2s        = (const float*)d_in[11];
    const float* w2v        = (const float*)d_in[12];
    float* out = (float*)d_out;

    int n_nodes = in_sizes[0] / 128;
    int n_edges = in_sizes[3];
    int nrt = (n_edges + 15) / 16;                 // 16-edge row tiles
    int nwave = (nrt + TPW - 1) / TPW;
    int nblk = (nwave + 3) / 4;

    char* p = (char*)d_ws;
    auto alloc = [&](size_t bytes, size_t align) -> void* {
        size_t a = (size_t)p; a = (a + align - 1) & ~(align - 1);
        p = (char*)a; void* r = (void*)p; p += bytes; return r;
    };
    float* xsv1 = (float*)alloc((size_t)n_nodes * 128 * 4, 16);
    float* W1s  = (float*)alloc(512 * 4, 16);
    float* W2T  = (float*)alloc(8192 * 4, 16);
    float* mid  = (float*)alloc((size_t)n_nodes * 256 * 4, 16);   // fallback only
    int* counts = (int*)alloc((size_t)n_nodes * 4, 16);
    int* offs   = (int*)alloc(((size_t)n_nodes + 1) * 4, 16);
    int* cursor = (int*)alloc((size_t)n_nodes * 4, 16);
    int* esrc_s = (int*)alloc(((size_t)n_edges + 4) * 4, 16);     // +4 lookahead pad
    float4* eattr_s = (float4*)alloc((size_t)n_edges * 16, 16);
    float4* escal_s = (float4*)alloc((size_t)n_edges * 32, 16);
    unsigned short* W2Tb = (unsigned short*)alloc(8192 * 2, 64);
    unsigned short* wbuf = (unsigned short*)alloc((size_t)nrt * 8 * 256 * 2, 64);
    size_t needed = (size_t)(p - (char*)d_ws);

    if (ws_size >= needed) {
        hipMemsetAsync(counts, 0, (size_t)n_nodes * sizeof(int), stream);
        pre_kernel<<<2048, 256, 0, stream>>>(
            node_input, attr_in, w1s, w1v, xsv1, n_nodes,
            Wfc1, Wfc2, W1s, W2T, W2Tb, edst, counts, n_edges);
        scan_kernel<<<1, 1024, 0, stream>>>(counts, offs, cursor, n_nodes);
        scatter_kernel<<<(n_edges + 255) / 256, 256, 0, stream>>>(
            edst, esrc, eattr, escal, cursor, esrc_s, eattr_s, escal_s, n_edges);
        edge_mlp_v4<<<nblk, 256, 0, stream>>>(escal_s, W1s, W2Tb, wbuf, n_edges, nrt);
        gather_out_kernel<<<(n_nodes + 3) / 4, 256, 0, stream>>>(
            wbuf, xsv1, esrc_s, eattr_s, offs, attr_out, w2s, w2v, out, n_nodes);
    } else {
        pre_kernel<<<2048, 256, 0, stream>>>(
            node_input, attr_in, w1s, w1v, xsv1, n_nodes,
            Wfc1, Wfc2, W1s, W2T, W2Tb, edst, counts, 0 /*no count*/);
        hipMemsetAsync(mid, 0, (size_t)n_nodes * 256 * sizeof(float), stream);
        edge_kernel_atomic<<<(n_edges + 255) / 256, 256, 0, stream>>>(
            xsv1, esrc, edst, eattr, escal, W1s, W2T, mid, n_edges);
        node_out_kernel<<<2048, 256, 0, stream>>>(mid, attr_out, w2s, w2v, out, n_nodes);
    }
}

// Round 24
// 243.024 us; speedup vs baseline: 1.4524x; 1.0153x over previous
//
#include <hip/hip_runtime.h>

// Convolution_1228360646680 — equivariant graph conv
// N=25000, E=400000, MUL=32, NSC=8, HID=64
//
// Fast path (6 dispatches):
//   memset(counts)
//   pre:      fused prep + edge count + node_in (8-row LDS staging)
//   scan:     offs/cursor prefix sum (1 block)
//   scatter:  dst-sorted permutation, payload written directly
//   edge_mlp_v4: wave = 8 consecutive 16-edge tiles; B-frags once/wave;
//             C-frags RAW tile layout (coalesced uint2, no LDS)
//   gather_out: WAVE per node (4/block); unroll-2 A/B pipeline (no rotation
//             moves, depth-1 prefetch, named regs); branch-free x loads;
//             accs -> LDS smid; fused w2 tail -> out.
// Fallback (ws too small): atomic scatter-add + node_out.

typedef __attribute__((ext_vector_type(8))) short bf16x8;
typedef __attribute__((ext_vector_type(4))) float f32x4;

__device__ __forceinline__ unsigned bf16r(float x) {
    unsigned u = __float_as_uint(x);
    return (u + 0x7fffu + ((u >> 16) & 1u)) >> 16;   // RNE
}
__device__ __forceinline__ float bflo(unsigned p) { return __uint_as_float(p << 16); }
__device__ __forceinline__ float bfhi(unsigned p) { return __uint_as_float(p & 0xffff0000u); }

// ---------------- fused: prep + count + node_in (8-row staging) ----------------
__global__ __launch_bounds__(256) void pre_kernel(
    const float* __restrict__ node_input, const float* __restrict__ attr_in,
    const float* __restrict__ w1s, const float* __restrict__ w1v,
    float* __restrict__ xsv1, int n_nodes,
    const float* __restrict__ Wfc1, const float* __restrict__ Wfc2,
    float* __restrict__ W1s, float* __restrict__ W2T, unsigned short* __restrict__ W2Tb,
    const int* __restrict__ edst, int* __restrict__ counts, int n_edges_count)
{
    int t = blockIdx.x * 256 + threadIdx.x;
    const float inv_sqrt_nsc = 0.35355339059327373f; // 1/sqrt(8)
    if (t < 8 * 64) W1s[t] = Wfc1[t] * inv_sqrt_nsc;
    if (t < 64 * 128) {
        int r = t >> 7, c = t & 127;
        float v = Wfc2[t] * 0.125f;                  // 1/sqrt(64)
        W2T[c * 64 + r] = v;
        W2Tb[c * 64 + r] = (unsigned short)bf16r(v);
    }
    for (int e = t; e < n_edges_count; e += gridDim.x * 256)
        atomicAdd(&counts[edst[e]], 1);

    __shared__ float sWs[1024], sWv[1024], srow[8][128];
    for (int k = threadIdx.x; k < 1024; k += 256) { sWs[k] = w1s[k]; sWv[k] = w1v[k]; }
    int tid = threadIdx.x;
    int j = tid & 127;
    int half = tid >> 7;
    int w = 0, i = 0;
    if (j >= 32) { int jj = j - 32; w = jj / 3; i = jj - 3 * w; }
    const float inv1 = 0.17677669529663687f; // 1/sqrt(32)
    for (int base = blockIdx.x * 8; base < n_nodes; base += gridDim.x * 8) {
        __syncthreads();   // guards srow reuse (and sWs/sWv on first iter)
        for (int idx = tid; idx < 1024; idx += 256) {
            int r = idx >> 7, c = idx & 127;
            int n = base + r;
            if (n < n_nodes) srow[r][c] = node_input[(size_t)n * 128 + c];
        }
        __syncthreads();
        #pragma unroll
        for (int rr = 0; rr < 4; rr++) {
            int r = 2 * rr + half;
            int n = base + r;
            if (n < n_nodes) {
                float acc = 0.0f;
                if (j < 32) {
                    #pragma unroll
                    for (int u = 0; u < 32; u++) acc += srow[r][u] * sWs[u * 32 + j];
                } else {
                    #pragma unroll
                    for (int u = 0; u < 32; u++) acc += srow[r][32 + 3 * u + i] * sWv[u * 32 + w];
                }
                xsv1[(size_t)n * 128 + j] = acc * (attr_in[n] * inv1);
            }
        }
    }
}

// ---------------- CSR build ----------------
__global__ __launch_bounds__(1024) void scan_kernel(
    const int* __restrict__ counts, int* __restrict__ offs, int* __restrict__ cursor, int n)
{
    __shared__ int part[1024];
    int tid = threadIdx.x;
    int chunk = (n + 1023) / 1024;
    int begin = tid * chunk;
    int end = begin + chunk; if (end > n) end = n;
    int s = 0;
    for (int i = begin; i < end; i++) s += counts[i];
    part[tid] = s;
    __syncthreads();
    for (int off = 1; off < 1024; off <<= 1) {
        int v = (tid >= off) ? part[tid - off] : 0;
        __syncthreads();
        part[tid] += v;
        __syncthreads();
    }
    int base = (tid == 0) ? 0 : part[tid - 1];
    for (int i = begin; i < end; i++) {
        offs[i] = base; cursor[i] = base;
        base += counts[i];
    }
    if (tid == 1023) offs[n] = part[1023];
}

__global__ __launch_bounds__(256) void scatter_kernel(
    const int* __restrict__ edst, const int* __restrict__ esrc,
    const float* __restrict__ eattr, const float* __restrict__ escal,
    int* __restrict__ cursor,
    int* __restrict__ esrc_s, float4* __restrict__ eattr_s, float4* __restrict__ escal_s,
    int n_edges)
{
    int e = blockIdx.x * 256 + threadIdx.x;
    if (e < n_edges) {
        int d = edst[e];
        int p = atomicAdd(&cursor[d], 1);
        esrc_s[p] = esrc[e];
        eattr_s[p] = *reinterpret_cast<const float4*>(eattr + (size_t)e * 4);
        escal_s[2 * (size_t)p]     = *reinterpret_cast<const float4*>(escal + (size_t)e * 8);
        escal_s[2 * (size_t)p + 1] = *reinterpret_cast<const float4*>(escal + (size_t)e * 8 + 4);
    }
}

// ---------------- edge MLP via MFMA, 8 tiles/wave -> raw C-frag tile layout ----------------
// wbuf[(rt*8+ct)*256 + l*4 + reg], l = ((m>>2)<<4)|nn, reg = m&3  (m=k&15, nn=col&15)
#define TPW 8
__global__ __launch_bounds__(256) void edge_mlp_v4(
    const float4* __restrict__ escal_s,
    const float* __restrict__ W1s, const unsigned short* __restrict__ W2Tb,
    unsigned short* __restrict__ wbuf, int n_edges, int nrt)
{
    int tid = threadIdx.x;
    int wv = tid >> 6, l = tid & 63;
    int lm = l & 15, lk = l >> 4;
    int k0 = lk * 8;
    int rt0 = (blockIdx.x * 4 + wv) * TPW;

    bf16x8 bf[8][2];
    #pragma unroll
    for (int t = 0; t < 8; t++) {
        int n = t * 16 + lm;
        bf[t][0] = *reinterpret_cast<const bf16x8*>(W2Tb + n * 64 + k0);
        bf[t][1] = *reinterpret_cast<const bf16x8*>(W2Tb + n * 64 + k0 + 32);
    }

    #pragma unroll 2
    for (int t8 = 0; t8 < TPW; t8++) {
        int rt = rt0 + t8;
        if (rt >= nrt) break;
        int kidx = rt * 16 + lm;

        float q[8];
        if (kidx < n_edges) {
            float4 qa = escal_s[2 * (size_t)kidx];
            float4 qb = escal_s[2 * (size_t)kidx + 1];
            q[0] = qa.x; q[1] = qa.y; q[2] = qa.z; q[3] = qa.w;
            q[4] = qb.x; q[5] = qb.y; q[6] = qb.z; q[7] = qb.w;
        } else {
            #pragma unroll
            for (int i = 0; i < 8; i++) q[i] = 0.f;
        }

        union Af { bf16x8 v; unsigned u[4]; };
        Af af0, af1;
        #pragma unroll
        for (int half = 0; half < 2; half++) {
            int kb = k0 + half * 32;
            float h[8];
            #pragma unroll
            for (int i = 0; i < 8; i++) h[i] = 0.f;
            #pragma unroll
            for (int in = 0; in < 8; in++) {
                float qi = q[in];
                float4 wa = *reinterpret_cast<const float4*>(W1s + in * 64 + kb);
                float4 wb = *reinterpret_cast<const float4*>(W1s + in * 64 + kb + 4);
                h[0] += qi * wa.x; h[1] += qi * wa.y; h[2] += qi * wa.z; h[3] += qi * wa.w;
                h[4] += qi * wb.x; h[5] += qi * wb.y; h[6] += qi * wb.z; h[7] += qi * wb.w;
            }
            unsigned* dst = half ? af1.u : af0.u;
            #pragma unroll
            for (int p = 0; p < 4; p++) {
                float s0 = h[2 * p], s1 = h[2 * p + 1];
                s0 = s0 / (1.0f + __expf(-s0));
                s1 = s1 / (1.0f + __expf(-s1));
                dst[p] = bf16r(s0) | (bf16r(s1) << 16);
            }
        }

        #pragma unroll
        for (int t = 0; t < 8; t++) {
            f32x4 a4 = {0.f, 0.f, 0.f, 0.f};
            a4 = __builtin_amdgcn_mfma_f32_16x16x32_bf16(af0.v, bf[t][0], a4, 0, 0, 0);
            a4 = __builtin_amdgcn_mfma_f32_16x16x32_bf16(af1.v, bf[t][1], a4, 0, 0, 0);
            unsigned s0 = bf16r(a4[0]) | (bf16r(a4[1]) << 16);
            unsigned s1 = bf16r(a4[2]) | (bf16r(a4[3]) << 16);
            *reinterpret_cast<uint2*>(wbuf + ((size_t)(rt * 8 + t) * 256) + l * 4) = make_uint2(s0, s1);
        }
    }
}

// ---------------- gather + fused node_out: wave/node, 4/block, unroll-2 A/B ----------------
__global__ __launch_bounds__(256) void gather_out_kernel(
    const unsigned short* __restrict__ wbuf, const float* __restrict__ xsv1,
    const int* __restrict__ esrc_s, const float4* __restrict__ eattr_s,
    const int* __restrict__ offs, const float* __restrict__ attr_out,
    const float* __restrict__ w2s, const float* __restrict__ w2v,
    float* __restrict__ out, int n_nodes)
{
    __shared__ float sW[4096];        // w2s (2048) | w2v (2048)
    __shared__ float smid[4][256];

    int tid = threadIdx.x;
    for (int idx = tid; idx < 2048; idx += 256) { sW[idx] = w2s[idx]; sW[2048 + idx] = w2v[idx]; }

    int wv = __builtin_amdgcn_readfirstlane(tid >> 6);
    int L = tid & 63;
    int n = blockIdx.x * 4 + wv;
    int g = L >> 4;

    int be, fbase; bool six;
    if (g == 0)      { be = 2 * L;       fbase = 2 * L;      six = false; }
    else if (g == 1) { be = 2 * L - 32;  fbase = 6 * L - 32; six = true;  }
    else if (g == 2) { be = 6 * L - 160; fbase = 6 * L - 32; six = true;  }
    else             { be = 6 * L - 256; fbase = 2 * L - 64; six = false; }

    const int colpart = ((2 * L) >> 4) * 256 + (((2 * L) & 15) << 2);
    const float inv_sqrt3 = 0.5773502691896258f;
    float a0 = 0.f, a1 = 0.f, a2 = 0.f, a3 = 0.f, a4 = 0.f, a5 = 0.f;

    if (n < n_nodes) {
        int start = offs[n], end = offs[n + 1];

        // load edge kk's operands into named regs (branch-free; be+5 < 128 for all g)
        #define GLOAD(EA, WQ, SEL, X0, X1, X2, KK)                                        \
        {                                                                                 \
            EA = eattr_s[KK];                                                             \
            int epart_ = ((KK) >> 4) * 2048 + ((((KK) >> 2) & 3) << 6);                   \
            SEL = (KK) & 3;                                                               \
            WQ = *reinterpret_cast<const uint4*>(wbuf + (size_t)epart_ + colpart);        \
            int src_ = esrc_s[KK];                                                        \
            const float* __restrict__ nb_ = xsv1 + (size_t)src_ * 128;                    \
            X0 = *reinterpret_cast<const float2*>(nb_ + be);                              \
            X1 = *reinterpret_cast<const float2*>(nb_ + be + 2);                          \
            X2 = *reinterpret_cast<const float2*>(nb_ + be + 4);                          \
        }

        #define GCOMP(EA, WQ, SEL, X0, X1, X2)                                            \
        {                                                                                 \
            unsigned ulo = ((SEL) & 2) ? (WQ).y : (WQ).x;                                 \
            unsigned uhi = ((SEL) & 2) ? (WQ).w : (WQ).z;                                 \
            float wlo = ((SEL) & 1) ? bfhi(ulo) : bflo(ulo);                              \
            float whi = ((SEL) & 1) ? bfhi(uhi) : bflo(uhi);                              \
            if (g == 0) {                                                                 \
                a0 += wlo * (X0).x * (EA).x;                                              \
                a1 += whi * (X0).y * (EA).x;                                              \
            } else if (g == 1) {                                                          \
                float b0 = wlo * (X0).x, b1 = whi * (X0).y;                               \
                a0 += b0 * (EA).y; a1 += b0 * (EA).z; a2 += b0 * (EA).w;                  \
                a3 += b1 * (EA).y; a4 += b1 * (EA).z; a5 += b1 * (EA).w;                  \
            } else if (g == 2) {                                                          \
                float b0 = wlo * (EA).x, b1 = whi * (EA).x;                               \
                a0 += b0 * (X0).x; a1 += b0 * (X0).y; a2 += b0 * (X1).x;                  \
                a3 += b1 * (X1).y; a4 += b1 * (X2).x; a5 += b1 * (X2).y;                  \
            } else {                                                                      \
                a0 += wlo * ((X0).x * (EA).y + (X0).y * (EA).z + (X1).x * (EA).w) * inv_sqrt3; \
                a1 += whi * ((X1).y * (EA).y + (X2).x * (EA).z + (X2).y * (EA).w) * inv_sqrt3; \
            }                                                                             \
        }

        if (start < end) {
            // unroll-2 A/B alternation: no rotation moves, depth-1 prefetch preserved
            float4 eaA; uint4 wqA; int selA; float2 xA0, xA1, xA2;
            float4 eaB; uint4 wqB; int selB; float2 xB0, xB1, xB2;
            GLOAD(eaA, wqA, selA, xA0, xA1, xA2, start);
            int k = start + 1;
            for (; k + 1 <= end - 1; k += 2) {
                GLOAD(eaB, wqB, selB, xB0, xB1, xB2, k);         // prefetch k
                GCOMP(eaA, wqA, selA, xA0, xA1, xA2);            // compute k-1
                GLOAD(eaA, wqA, selA, xA0, xA1, xA2, k + 1);     // prefetch k+1
                GCOMP(eaB, wqB, selB, xB0, xB1, xB2);            // compute k
            }
            if (k < end) {
                GLOAD(eaB, wqB, selB, xB0, xB1, xB2, k);
                GCOMP(eaA, wqA, selA, xA0, xA1, xA2);
                GCOMP(eaB, wqB, selB, xB0, xB1, xB2);
            } else {
                GCOMP(eaA, wqA, selA, xA0, xA1, xA2);
            }
        }
        #undef GLOAD
        #undef GCOMP
    }

    float* row = &smid[wv][fbase];
    row[0] = a0; row[1] = a1;
    if (six) { row[2] = a2; row[3] = a3; row[4] = a4; row[5] = a5; }
    __syncthreads();   // covers sW staging + smid writes

    int h = tid >> 7, j = tid & 127;
    int tw = 0, ti = 0;
    if (j >= 32) { int jj = j - 32; tw = jj / 3; ti = jj - 3 * tw; }
    #pragma unroll
    for (int it = 0; it < 2; it++) {
        int ln = 2 * it + h;
        int nn = blockIdx.x * 4 + ln;
        if (nn < n_nodes) {
            const float* __restrict__ sm = smid[ln];
            float o = 0.0f;
            if (j < 32) {
                #pragma unroll
                for (int u = 0; u < 32; u++)
                    o += sm[u] * sW[u * 32 + j] + sm[32 + u] * sW[1024 + u * 32 + j];
            } else {
                #pragma unroll
                for (int u = 0; u < 32; u++)
                    o += sm[64 + 3 * u + ti] * sW[2048 + u * 32 + tw]
                       + sm[160 + 3 * u + ti] * sW[3072 + u * 32 + tw];
            }
            out[(size_t)nn * 128 + j] = o * (attr_out[nn] * 0.03125f); // 1/sqrt(64)/sqrt(16)
        }
    }
}

// ---------------- fallback atomic edge kernel (ws too small) ----------------
__global__ __launch_bounds__(256) void edge_kernel_atomic(
    const float* __restrict__ xsv1, const int* __restrict__ esrc, const int* __restrict__ edst,
    const float* __restrict__ eattr, const float* __restrict__ escal,
    const float* __restrict__ W1s, const float* __restrict__ W2T,
    float* __restrict__ mid, int n_edges)
{
    int e = blockIdx.x * 256 + threadIdx.x;
    if (e >= n_edges) return;
    const float4 qa = *reinterpret_cast<const float4*>(escal + (size_t)e * 8);
    const float4 qb = *reinterpret_cast<const float4*>(escal + (size_t)e * 8 + 4);
    float h[64];
    #pragma unroll
    for (int t = 0; t < 64; t++) {
        float acc = qa.x * W1s[t]       + qa.y * W1s[64 + t]
                  + qa.z * W1s[128 + t] + qa.w * W1s[192 + t]
                  + qb.x * W1s[256 + t] + qb.y * W1s[320 + t]
                  + qb.z * W1s[384 + t] + qb.w * W1s[448 + t];
        h[t] = acc / (1.0f + __expf(-acc));
    }
    int src = esrc[e], dst = edst[e];
    const float4 ea = *reinterpret_cast<const float4*>(eattr + (size_t)e * 4);
    const float ys = ea.x, yv0 = ea.y, yv1 = ea.z, yv2 = ea.w;
    const float* __restrict__ nb = xsv1 + (size_t)src * 128;
    float* __restrict__ op = mid + (size_t)dst * 256;
    const float inv_sqrt3 = 0.5773502691896258f;
    for (int u = 0; u < 32; u++) {
        float w0 = 0.f, w1 = 0.f, w2 = 0.f, w3 = 0.f;
        const float* __restrict__ r0 = W2T + (size_t)u * 64;
        const float* __restrict__ r1 = W2T + (size_t)(32 + u) * 64;
        const float* __restrict__ r2 = W2T + (size_t)(64 + u) * 64;
        const float* __restrict__ r3 = W2T + (size_t)(96 + u) * 64;
        #pragma unroll
        for (int t = 0; t < 64; t++) {
            float hv = h[t];
            w0 += hv * r0[t]; w1 += hv * r1[t]; w2 += hv * r2[t]; w3 += hv * r3[t];
        }
        float es  = nb[u];
        float ev0 = nb[32 + 3 * u], ev1 = nb[33 + 3 * u], ev2 = nb[34 + 3 * u];
        atomicAdd(op + u,      w0 * es * ys);
        atomicAdd(op + 32 + u, w3 * (ev0 * yv0 + ev1 * yv1 + ev2 * yv2) * inv_sqrt3);
        float a1 = w1 * es;
        atomicAdd(op + 64 + 3 * u, a1 * yv0);
        atomicAdd(op + 65 + 3 * u, a1 * yv1);
        atomicAdd(op + 66 + 3 * u, a1 * yv2);
        float a2 = w2 * ys;
        atomicAdd(op + 160 + 3 * u, a2 * ev0);
        atomicAdd(op + 161 + 3 * u, a2 * ev1);
        atomicAdd(op + 162 + 3 * u, a2 * ev2);
    }
}

__global__ __launch_bounds__(256) void node_out_kernel(
    const float* __restrict__ mid, const float* __restrict__ attr_out,
    const float* __restrict__ w2s, const float* __restrict__ w2v,
    float* __restrict__ out, int n_nodes)
{
    __shared__ float sS0[1024], sS1[1024], sV0[1024], sV1[1024];
    for (int k = threadIdx.x; k < 1024; k += 256) {
        sS0[k] = w2s[k]; sS1[k] = w2s[1024 + k];
        sV0[k] = w2v[k]; sV1[k] = w2v[1024 + k];
    }
    __syncthreads();
    int j = threadIdx.x & 127;
    int half = threadIdx.x >> 7;
    int w = 0, i = 0;
    if (j >= 32) { int jj = j - 32; w = jj / 3; i = jj - 3 * w; }
    const float scale = 0.125f * 0.25f;
    for (int base = blockIdx.x * 2; base < n_nodes; base += gridDim.x * 2) {
        int n = base + half;
        if (n >= n_nodes) continue;
        const float* __restrict__ mr = mid + (size_t)n * 256;
        float acc = 0.0f;
        if (j < 32) {
            #pragma unroll
            for (int u = 0; u < 32; u++)
                acc += mr[u] * sS0[u * 32 + j] + mr[32 + u] * sS1[u * 32 + j];
        } else {
            #pragma unroll
            for (int u = 0; u < 32; u++)
                acc += mr[64 + 3 * u + i] * sV0[u * 32 + w] + mr[160 + 3 * u + i] * sV1[u * 32 + w];
        }
        out[(size_t)n * 128 + j] = acc * (attr_out[n] * scale);
    }
}

extern "C" void kernel_launch(void* const* d_in, const int* in_sizes, int n_in,
                              void* d_out, int out_size, void* d_ws, size_t ws_size,
                              hipStream_t stream)
{
    const float* node_input = (const float*)d_in[0];
    const float* attr_in    = (const float*)d_in[1];
    const float* attr_out   = (const float*)d_in[2];
    const int*   esrc       = (const int*)d_in[3];
    const int*   edst       = (const int*)d_in[4];
    const float* eattr      = (const float*)d_in[5];
    const float* escal      = (const float*)d_in[6];
    const float* w1s        = (const float*)d_in[7];
    const float* w1v        = (const float*)d_in[8];
    const float* Wfc1       = (const float*)d_in[9];
    const float* Wfc2       = (const float*)d_in[10];
    const float* w2s        = (const float*)d_in[11];
    const float* w2v        = (const float*)d_in[12];
    float* out = (float*)d_out;

    int n_nodes = in_sizes[0] / 128;
    int n_edges = in_sizes[3];
    int nrt = (n_edges + 15) / 16;                 // 16-edge row tiles
    int nwave = (nrt + TPW - 1) / TPW;
    int nblk = (nwave + 3) / 4;

    char* p = (char*)d_ws;
    auto alloc = [&](size_t bytes, size_t align) -> void* {
        size_t a = (size_t)p; a = (a + align - 1) & ~(align - 1);
        p = (char*)a; void* r = (void*)p; p += bytes; return r;
    };
    float* xsv1 = (float*)alloc((size_t)n_nodes * 128 * 4, 16);
    float* W1s  = (float*)alloc(512 * 4, 16);
    float* W2T  = (float*)alloc(8192 * 4, 16);
    float* mid  = (float*)alloc((size_t)n_nodes * 256 * 4, 16);   // fallback only
    int* counts = (int*)alloc((size_t)n_nodes * 4, 16);
    int* offs   = (int*)alloc(((size_t)n_nodes + 1) * 4, 16);
    int* cursor = (int*)alloc((size_t)n_nodes * 4, 16);
    int* esrc_s = (int*)alloc(((size_t)n_edges + 4) * 4, 16);     // +4 lookahead pad
    float4* eattr_s = (float4*)alloc((size_t)n_edges * 16, 16);
    float4* escal_s = (float4*)alloc((size_t)n_edges * 32, 16);
    unsigned short* W2Tb = (unsigned short*)alloc(8192 * 2, 64);
    unsigned short* wbuf = (unsigned short*)alloc((size_t)nrt * 8 * 256 * 2, 64);
    size_t needed = (size_t)(p - (char*)d_ws);

    if (ws_size >= needed) {
        hipMemsetAsync(counts, 0, (size_t)n_nodes * sizeof(int), stream);
        pre_kernel<<<2048, 256, 0, stream>>>(
            node_input, attr_in, w1s, w1v, xsv1, n_nodes,
            Wfc1, Wfc2, W1s, W2T, W2Tb, edst, counts, n_edges);
        scan_kernel<<<1, 1024, 0, stream>>>(counts, offs, cursor, n_nodes);
        scatter_kernel<<<(n_edges + 255) / 256, 256, 0, stream>>>(
            edst, esrc, eattr, escal, cursor, esrc_s, eattr_s, escal_s, n_edges);
        edge_mlp_v4<<<nblk, 256, 0, stream>>>(escal_s, W1s, W2Tb, wbuf, n_edges, nrt);
        gather_out_kernel<<<(n_nodes + 3) / 4, 256, 0, stream>>>(
            wbuf, xsv1, esrc_s, eattr_s, offs, attr_out, w2s, w2v, out, n_nodes);
    } else {
        pre_kernel<<<2048, 256, 0, stream>>>(
            node_input, attr_in, w1s, w1v, xsv1, n_nodes,
            Wfc1, Wfc2, W1s, W2T, W2Tb, edst, counts, 0 /*no count*/);
        hipMemsetAsync(mid, 0, (size_t)n_nodes * 256 * sizeof(float), stream);
        edge_kernel_atomic<<<(n_edges + 255) / 256, 256, 0, stream>>>(
            xsv1, esrc, edst, eattr, escal, W1s, W2T, mid, n_edges);
        node_out_kernel<<<2048, 256, 0, stream>>>(mid, attr_out, w2s, w2v, out, n_nodes);
    }
}